// Round 5
// baseline (865.220 us; speedup 1.0000x reference)
//
#include <hip/hip_runtime.h>

// sizes: B=8, N=5, C=256, H*W=4096, PIX = 32768 global pixels
typedef __attribute__((ext_vector_type(8))) short short8;
typedef __attribute__((ext_vector_type(4))) float f32x4;
typedef __attribute__((ext_vector_type(8))) unsigned short us8;
typedef __attribute__((ext_vector_type(4))) unsigned short us4;
typedef __attribute__((ext_vector_type(2))) unsigned short us2;

__device__ __forceinline__ float sigmoidf_(float x){ return 1.f/(1.f+__expf(-x)); }
__device__ __forceinline__ unsigned short f2bf(float f){
    union{float f; unsigned int u;} x; x.f = f;
    unsigned int r = x.u + 0x7fffu + ((x.u>>16)&1u);
    return (unsigned short)(r>>16);
}
__device__ __forceinline__ float bf2f(unsigned short u){
    union{unsigned int u; float f;} x; x.u = ((unsigned int)u)<<16; return x.f;
}
#define GAS(p) ((const __attribute__((address_space(1))) void*)(uintptr_t)(p))
#define LAS(p) ((__attribute__((address_space(3))) void*)(uintptr_t)(p))

#define SLOT 8388608ull   // per-slot stride in ushorts

// Weight prep, both matrices in one launch.
// dst blocked [kb][OCN][64] bf16, chunk-XOR-swizzled by (oc&7).
__global__ __launch_bounds__(256) void k_wp2(const float* __restrict__ w_u, const float* __restrict__ w_r,
                                             const float* __restrict__ w_o,
                                             unsigned short* __restrict__ Wc0, unsigned short* __restrict__ Wc1){
    int bx = blockIdx.x;
    const float *s0, *s1; unsigned short* dst; int OCN, tid;
    if (bx < 256){ tid = bx*256 + threadIdx.x; OCN = 512; s0 = w_u; s1 = w_r; dst = Wc0; }
    else         { tid = (bx-256)*256 + threadIdx.x; OCN = 256; s0 = w_o; s1 = w_o; dst = Wc1; }
    int d = tid*4;
    int kk = d & 63;
    int row = d >> 6;
    int oc = row & (OCN-1);
    int kb = row / OCN;
    int k  = kb*64 + kk;
    const float* src = (oc < 256) ? s0 : s1;
    int ocr = (oc < 256) ? oc : oc-256;
    float4 v = *(const float4*)&src[(size_t)ocr*512 + k];
    us4 pk; pk.x=f2bf(v.x); pk.y=f2bf(v.y); pk.z=f2bf(v.z); pk.w=f2bf(v.w);
    int kk_sw = kk ^ ((oc&7)<<3);
    *(us4*)&dst[(size_t)row*64 + kk_sw] = pk;
}

// Fused dots+sum+gate+pack. Block = 32 px, all 256 c, all 5 n.
__global__ __launch_bounds__(256) void k_bxsd(const float* __restrict__ inp, const float* __restrict__ wgt,
                                              unsigned short* __restrict__ Alo, unsigned short* __restrict__ Ahi,
                                              int i0, int cnt){
    __shared__ float wg[1024];
    __shared__ float dpart[8*640];     // [cg][(n*4+j)*32 + px]
    __shared__ float Dl[640];          // [(n*4+j)*32 + px]
    __shared__ unsigned short tm[64*34];
    __shared__ unsigned short th[64*34];
    int t  = threadIdx.x;
    int p0 = blockIdx.x << 5;
    int b  = p0 >> 12, pl0 = p0 & 4095;
    for (int s=t; s<1024; s+=256) wg[s] = wgt[s];
    __syncthreads();
    // pass A: D[b,n,j,px] = sum_c inp[b,n,c,px]*wgt[j,c]
    {
        int px = t & 31, cg = t >> 5;
        float d[20];
        #pragma unroll
        for (int o=0;o<20;o++) d[o]=0.f;
        #pragma unroll
        for (int cc=0; cc<32; cc++){
            int c = cg*32 + cc;
            float w0 = wg[c], w1 = wg[256+c], w2 = wg[512+c], w3 = wg[768+c];
            #pragma unroll
            for (int n=0;n<5;n++){
                float v = inp[(((size_t)((b*5+n)*256+c))<<12) + pl0 + px];
                d[n*4+0] += v*w0; d[n*4+1] += v*w1; d[n*4+2] += v*w2; d[n*4+3] += v*w3;
            }
        }
        #pragma unroll
        for (int o=0;o<20;o++) dpart[cg*640 + o*32 + px] = d[o];
    }
    __syncthreads();
    for (int o=t; o<640; o+=256){
        float s = 0.f;
        #pragma unroll
        for (int g=0; g<8; g++) s += dpart[g*640 + o];
        Dl[o] = s;
    }
    __syncthreads();
    // pass B
    for (int ct=0; ct<4; ct++){
        int c0 = ct << 6;
        f32x4 x[5][2], S4[2];
        #pragma unroll
        for (int q=0;q<2;q++){
            int s = t + q*256;
            int c = s >> 3, pc = (s&7) << 2;
            int cc = c0 + c;
            f32x4 acc = {0.f,0.f,0.f,0.f};
            #pragma unroll
            for (int n=0;n<5;n++){
                x[n][q] = *(const f32x4*)&inp[(((size_t)((b*5+n)*256+cc))<<12) + pl0 + pc];
                acc += x[n][q];
            }
            S4[q] = acc;
        }
        #pragma unroll
        for (int i=0;i<5;i++){
            if (i < i0 || i >= i0+cnt) continue;
            #pragma unroll
            for (int q=0;q<2;q++){
                int s = t + q*256;
                int c = s >> 3, pc = (s&7) << 2;
                int j = c & 3;
                int node = (j < i) ? j : (j+1);
                f32x4 dw = *(const f32x4*)&Dl[(i*4+j)*32 + pc];
                f32x4 dn = *(const f32x4*)&Dl[(node*4+j)*32 + pc];
                f32x4 xi = x[i][q];
                f32x4 md = S4[q] - xi;
                int lb = c*34 + pc;
                us2 m0, m1, h0, h1;
                m0.x = f2bf(sigmoidf_(dw.x-dn.x)*md.x); m0.y = f2bf(sigmoidf_(dw.y-dn.y)*md.y);
                m1.x = f2bf(sigmoidf_(dw.z-dn.z)*md.z); m1.y = f2bf(sigmoidf_(dw.w-dn.w)*md.w);
                h0.x = f2bf(xi.x); h0.y = f2bf(xi.y); h1.x = f2bf(xi.z); h1.y = f2bf(xi.w);
                *(us2*)&tm[lb] = m0; *(us2*)&tm[lb+2] = m1;
                *(us2*)&th[lb] = h0; *(us2*)&th[lb+2] = h1;
            }
            __syncthreads();
            {
                int p = t >> 3, cs = (t&7) << 3;
                us8 vm, vh;
                #pragma unroll
                for (int j8=0;j8<8;j8++){ vm[j8] = tm[(cs+j8)*34 + p]; vh[j8] = th[(cs+j8)*34 + p]; }
                int cs_sw = cs ^ ((p&7)<<3);
                size_t dst = (size_t)(i - i0)*SLOT + ((size_t)ct*32768 + p0 + p)*64 + cs_sw;
                *(us8*)&Alo[dst] = vm;
                *(us8*)&Ahi[dst] = vh;
            }
            __syncthreads();
        }
    }
}

// MFMA GEMM: D[oc][p] = sum_k W[oc][k]*Act[p][k].
// 256x256 tile, BK=64, 512 threads / 8 waves (2 oc-slabs x 4 p-slabs),
// per-wave output 128oc x 64p (8x4 frags of 16x16x32) -> 0.375 ds_read_b128
// per MFMA (vs 0.5 at 128^2): raises the LDS-bandwidth MfmaUtil ceiling ~2x.
// 2-deep stage-early double buffer (128 KiB LDS), one __syncthreads per step.
// Grid x: XCD-chunked, oc-fast. z = slot.
// U layout frag-native: zo + (p0>>8)*65536 + (fn*8+fm)*2048 + t*4 (+r), written by
// mm0 (oc0==0 blocks) and read back by mm1 with the identical formula.
// EPI0 (OCN=512): oc0=0   -> U = bf16(sigmoid(v+b_u))
//                 oc0=256 -> A1hi = bf16(sigmoid(v+b_r)*h_bf16-from-Ahi)
// EPI1 (OCN=256): out = (h*(1-u)+tanh(v+b_o)*u)*gamma + h   (h read f32: exact residual)
template<int EPI>
__global__ __launch_bounds__(512,2) void k_mm(
        const unsigned short* __restrict__ Alo, const unsigned short* __restrict__ Ahi,
        const unsigned short* __restrict__ Wb,
        const float* __restrict__ inp, const float* __restrict__ b0, const float* __restrict__ b1,
        unsigned short* __restrict__ U, unsigned short* __restrict__ A1hi, float* __restrict__ outp,
        const float* __restrict__ gamma_p, int i0)
{
    constexpr int OCN = EPI ? 256 : 512;
    constexpr int NY  = EPI ? 1   : 2;      // 256-wide oc tiles
    constexpr int NWG = 128*NY;             // blocks per z-slice
    __shared__ unsigned short As[2][256*64];   // weights tile [oc][64]
    __shared__ unsigned short Bs[2][256*64];   // pixel tile  [p][64]
    int t  = threadIdx.x, wv = t>>6, ln = t&63;

    // XCD-chunked remap, oc-fast within chunk (NWG multiple of 8 -> bijective)
    int bid = blockIdx.x;
    int wg  = (bid&7)*(NWG>>3) + (bid>>3);
    int oc0 = (wg & (NY-1)) * 256;
    int p0  = (wg / NY) * 256;

    int z  = blockIdx.z, i = i0 + z;
    size_t zo = (size_t)z*SLOT;
    int wm = (wv>>2)*128, wn = (wv&3)*64;
    int row = ln & 15, quad = ln >> 4, kq = quad*8;

    f32x4 acc[8][4];
    f32x4 zr = {0.f,0.f,0.f,0.f};
    #pragma unroll
    for (int a=0;a<8;a++){
        #pragma unroll
        for (int o=0;o<4;o++) acc[a][o]=zr;
    }

    auto stage = [&](int kb, int buf){
        const unsigned short* gA = (kb<4) ? (Alo + zo + ((size_t)kb*32768 + p0)*64)
                                          : (Ahi + zo + ((size_t)(kb-4)*32768 + p0)*64);
        const unsigned short* gW = Wb + ((size_t)kb*OCN + oc0)*64;
        #pragma unroll
        for (int q=0;q<4;q++){
            int idx = (q*512 + t)*8;        // 16B chunks, 0..32767 us
            __builtin_amdgcn_global_load_lds(GAS(gA + idx), LAS(&Bs[buf][idx]), 16, 0, 0);
            __builtin_amdgcn_global_load_lds(GAS(gW + idx), LAS(&As[buf][idx]), 16, 0, 0);
        }
    };

    stage(0, 0);
    __syncthreads();

    int rsw = (row&7)<<3;
    for (int kb=0; kb<8; ++kb){
        const int cur = kb & 1;
        if (kb < 7) stage(kb+1, cur^1);
        #pragma unroll
        for (int ks=0; ks<2; ks++){
            short8 a[8], b[4];
            int col = (ks*32 + kq) ^ rsw;
            #pragma unroll
            for (int f=0; f<8; f++)
                a[f] = *(const short8*)&As[cur][(wm+f*16+row)*64 + col];
            #pragma unroll
            for (int f=0; f<4; f++)
                b[f] = *(const short8*)&Bs[cur][(wn+f*16+row)*64 + col];
            __builtin_amdgcn_s_setprio(1);
            #pragma unroll
            for (int fm=0; fm<8; fm++){
                #pragma unroll
                for (int fn=0; fn<4; fn++)
                    acc[fm][fn] = __builtin_amdgcn_mfma_f32_16x16x32_bf16(a[fm], b[fn], acc[fm][fn], 0,0,0);
            }
            __builtin_amdgcn_s_setprio(0);
        }
        __syncthreads();     // drains staged loads; frees cur for kb+2
    }

    if (EPI==0){
        if (oc0 == 0){
            size_t ub = zo + (size_t)(p0>>8)*65536 + (size_t)t*4;
            #pragma unroll
            for (int fn=0; fn<4; fn++){
                #pragma unroll
                for (int fm=0; fm<8; fm++){
                    int ocb = wm + fm*16 + quad*4;
                    us4 pk;
                    #pragma unroll
                    for (int r=0;r<4;r++)
                        pk[r] = f2bf(sigmoidf_(acc[fm][fn][r] + b0[ocb+r]));
                    *(us4*)&U[ub + (size_t)(fn*8+fm)*2048] = pk;
                }
            }
        } else {
            #pragma unroll
            for (int fn=0; fn<4; fn++){
                int p = p0 + wn + fn*16 + row;
                int psw = (p&7)<<3;
                #pragma unroll
                for (int fm=0; fm<8; fm++){
                    int kb2 = wm + fm*16 + quad*4;         // oc-256, mult of 4
                    size_t aidx = zo + ((size_t)(kb2>>6)*32768 + p)*64 + ((kb2&63)^psw);
                    us4 vh = *(const us4*)&Ahi[aidx];
                    us4 pk;
                    #pragma unroll
                    for (int r=0;r<4;r++){
                        float rg = sigmoidf_(acc[fm][fn][r] + b1[kb2+r]);
                        pk[r] = f2bf(rg * bf2f(vh[r]));
                    }
                    *(us4*)&A1hi[aidx] = pk;
                }
            }
        }
    } else {
        float gm = gamma_p[0];
        size_t ub = zo + (size_t)(p0>>8)*65536 + (size_t)t*4;
        #pragma unroll
        for (int fn=0; fn<4; fn++){
            int p  = p0 + wn + fn*16 + row;
            int b  = p >> 12, pl = p & 4095;
            size_t hb = (((size_t)((b*5+i)*256))<<12) + pl;
            #pragma unroll
            for (int fm=0; fm<8; fm++){
                int ocb = wm + fm*16 + quad*4;
                us4 vu = *(const us4*)&U[ub + (size_t)(fn*8+fm)*2048];
                #pragma unroll
                for (int r=0;r<4;r++){
                    int oc = ocb + r;
                    float v  = acc[fm][fn][r] + b0[oc];
                    float e2 = __expf(2.f*v);
                    float thv = 1.f - 2.f/(e2+1.f);
                    float uu = bf2f(vu[r]);
                    float h  = inp[hb + ((size_t)oc<<12)];
                    float hn = h*(1.f-uu) + thv*uu;
                    outp[hb + ((size_t)oc<<12)] = hn*gm + h;
                }
            }
        }
    }
}

extern "C" void kernel_launch(void* const* d_in, const int* in_sizes, int n_in,
                              void* d_out, int out_size, void* d_ws, size_t ws_size,
                              hipStream_t stream) {
    const float* inputs = (const float*)d_in[0];
    const float* wgt_w  = (const float*)d_in[1];
    const float* w_r    = (const float*)d_in[2];
    const float* b_r    = (const float*)d_in[3];
    const float* w_u    = (const float*)d_in[4];
    const float* b_u    = (const float*)d_in[5];
    const float* w_o    = (const float*)d_in[6];
    const float* b_o    = (const float*)d_in[7];
    const float* gamma  = (const float*)d_in[8];
    float* out = (float*)d_out;

    unsigned short* Wc0 = (unsigned short*)d_ws;          // 512*512
    unsigned short* Wc1 = Wc0 + 262144;                   // 256*512
    unsigned short* U   = Wc1 + 131072;                   // nb slots x SLOT (bf16)

    size_t fixedB = (262144ull + 131072ull)*2;
    size_t slotB  = 4ull*SLOT*2;                          // U + Alo + Ahi + A1hi per slot
    int nb = 1;
    for (int k2=5;k2>=1;k2--){ if (fixedB + (size_t)k2*slotB <= ws_size){ nb = k2; break; } }

    unsigned short* Alo  = U   + (size_t)nb*SLOT;         // m_t blocked
    unsigned short* Ahi  = Alo + (size_t)nb*SLOT;         // h_t blocked
    unsigned short* A1hi = Ahi + (size_t)nb*SLOT;         // h*r blocked

    k_wp2 <<<384, 256, 0, stream>>>(w_u, w_r, w_o, Wc0, Wc1);
    for (int i0=0; i0<5; i0+=nb){
        int cnt = (5-i0 < nb) ? (5-i0) : nb;
        k_bxsd<<<1024, 256, 0, stream>>>(inputs, wgt_w, Alo, Ahi, i0, cnt);
        k_mm<0><<<dim3(256,1,cnt), 512, 0, stream>>>(Alo, Ahi, Wc0, inputs, b_u, b_r,
                                                     U, A1hi, nullptr, gamma, i0);
        k_mm<1><<<dim3(128,1,cnt), 512, 0, stream>>>(Alo, A1hi, Wc1, inputs, b_o, nullptr,
                                                     U, nullptr, out, gamma, i0);
    }
}